// Round 1
// baseline (717.010 us; speedup 1.0000x reference)
//
#include <hip/hip_runtime.h>
#include <hip/hip_cooperative_groups.h>
#include <math.h>

namespace cg = cooperative_groups;

#define BB 8
#define CC 256
#define HH 128
#define WW 128
#define HWP 16384          // 128*128
#define MH 512
#define MW 512
#define NPIX (BB*HWP)      // 131072
#define IQ 4096            // HWP/4 quads per image

#define TW 64
#define TH 4
#define IW 70
#define IH 10
#define PITCH 72

typedef float f32x4_t __attribute__((ext_vector_type(4)));

// ---------------------------------------------------------------------------
// Fused cooperative kernel: 1024 blocks x 256 threads, exactly 4 blocks/CU.
// Phase 1: even blocks mask-resize, odd blocks x channel partial sum/max.
// Phase 2: blocks <512 do the 7x7 conv + sigmoid -> wprod.
// Phase 3: each block handles 2 (b,c) planes: o=x*wprod, instnorm, relu(5*).
// grid.sync() replaces the two kernel-boundary drains; x (134MB) stays
// L3-resident across phases; out is written with nontemporal stores so the
// phase-3 writes don't evict x.
// ---------------------------------------------------------------------------
__global__ __launch_bounds__(256, 4) void fused(
    const float* __restrict__ masks, const float* __restrict__ x,
    const float* __restrict__ cw, const float* __restrict__ gamma,
    const float* __restrict__ beta, float* __restrict__ out,
    float* __restrict__ m_out, float* __restrict__ cs,
    float* __restrict__ cm, float* __restrict__ wprod)
{
    cg::grid_group grid = cg::this_grid();
    __shared__ float w[147];
    __shared__ float pa[IH * PITCH], px[IH * PITCH], pm[IH * PITCH];
    __shared__ float ls[4], lss[4], sstat[2];

    const int bid = blockIdx.x, tid = threadIdx.x;

    // ---------------- Phase 1: mask resize || channel reduce ----------------
    if ((bid & 1) == 0) {
        int t = (bid >> 1) * 256 + tid;            // 0..NPIX-1
        int j = t & 127, i = (t >> 7) & 127, b = t >> 14;
        const float Wt[8] = {1.f, 3.f, 5.f, 7.f, 7.f, 5.f, 3.f, 1.f};
        const float* mb = masks + (size_t)b * (MH * MW);
        int r0 = 4 * i - 2, c0 = 4 * j - 2;
        float cwgt[8];
        int ccl[8];
        float sh = 0.f;
        #pragma unroll
        for (int q = 0; q < 8; q++) {
            int c = c0 + q;
            bool v = (unsigned)c < (unsigned)MW;
            cwgt[q] = v ? Wt[q] : 0.f;
            sh += cwgt[q];
            ccl[q] = min(max(c, 0), MW - 1);
        }
        float acc = 0.f, sv = 0.f;
        #pragma unroll
        for (int p = 0; p < 8; p++) {
            int r = r0 + p;
            bool v = (unsigned)r < (unsigned)MH;
            float wp = v ? Wt[p] : 0.f;
            sv += wp;
            const float* row = mb + (size_t)min(max(r, 0), MH - 1) * MW;
            float ra = 0.f;
            #pragma unroll
            for (int q = 0; q < 8; q++) ra += cwgt[q] * row[ccl[q]];
            acc += wp * ra;
        }
        m_out[t] = acc / (sv * sh);
    } else {
        int id = bid >> 1;               // 0..511 = b(3) | g(2) | chunk(4)
        int chunk = id & 15;
        int g = (id >> 4) & 3;
        int b = id >> 6;
        int qi = chunk * 256 + tid;      // quad index within image
        const float4* xb = (const float4*)x + ((size_t)(b * CC + g * 64)) * IQ + qi;
        float4 s = {0.f, 0.f, 0.f, 0.f};
        float4 mx = {-INFINITY, -INFINITY, -INFINITY, -INFINITY};
        #pragma unroll 8
        for (int c = 0; c < 64; c++) {
            float4 v = xb[(size_t)c * IQ];
            s.x += v.x; s.y += v.y; s.z += v.z; s.w += v.w;
            mx.x = fmaxf(mx.x, v.x); mx.y = fmaxf(mx.y, v.y);
            mx.z = fmaxf(mx.z, v.z); mx.w = fmaxf(mx.w, v.w);
        }
        size_t o = (size_t)g * (NPIX / 4) + (size_t)b * IQ + qi;
        ((float4*)cs)[o] = s;
        ((float4*)cm)[o] = mx;
    }

    __threadfence();   // make phase-1 stores device-visible before release
    grid.sync();

    // ---------------- Phase 2: combine + 7x7 conv + sigmoid ----------------
    if (bid < 512) {
        int bx = bid & 1, by = (bid >> 1) & 31, b = bid >> 6;
        if (tid < 147) w[tid] = cw[tid];
        int ox = bx * TW - 3, oy = by * TH - 3;
        for (int idx = tid; idx < IW * IH; idx += 256) {
            int r = idx / IW, c = idx - r * IW;
            int gi = oy + r, gj = ox + c;
            float av = 0.f, mxv = 0.f, mv = 0.f;
            if ((unsigned)gi < (unsigned)HH && (unsigned)gj < (unsigned)WW) {
                int p = b * HWP + gi * WW + gj;
                mv = m_out[p];
                float sfull = cs[p] + cs[p + NPIX] + cs[p + 2 * NPIX] + cs[p + 3 * NPIX];
                float mmx = fmaxf(fmaxf(cm[p], cm[p + NPIX]),
                                  fmaxf(cm[p + 2 * NPIX], cm[p + 3 * NPIX]));
                av = mv * sfull * (1.f / 256.f);
                mxv = mv * mmx;
            }
            pa[r * PITCH + c] = av;
            px[r * PITCH + c] = mxv;
            pm[r * PITCH + c] = mv;
        }
        __syncthreads();
        int col = tid & 63, r = tid >> 6;
        float acc = 0.f;
        #pragma unroll
        for (int di = 0; di < 7; di++) {
            #pragma unroll
            for (int dj = 0; dj < 7; dj++) {
                int li = (r + di) * PITCH + col + dj;
                acc += w[di * 7 + dj] * pa[li];
                acc += w[49 + di * 7 + dj] * px[li];
                acc += w[98 + di * 7 + dj] * pm[li];
            }
        }
        float at = 1.f / (1.f + expf(-acc));
        float res = pm[(r + 3) * PITCH + col + 3] * at;
        wprod[b * HWP + (by * TH + r) * WW + bx * TW + col] = res;
    }

    __threadfence();
    grid.sync();

    // ---------------- Phase 3: o=x*wprod, instance-norm, relu(5*) ----------
    for (int bc = bid; bc < BB * CC; bc += 1024) {
        int b = bc >> 8, c = bc & 255;
        const float4* xp = (const float4*)(x + (size_t)bc * HWP);
        const float4* wpv = (const float4*)(wprod + (size_t)b * HWP);
        float4 o[16];
        float s = 0.f, ss = 0.f;
        #pragma unroll
        for (int k = 0; k < 16; k++) {
            int idx = tid + k * 256;
            float4 xv = xp[idx];
            float4 wv = wpv[idx];
            float4 ov;
            ov.x = xv.x * wv.x; ov.y = xv.y * wv.y;
            ov.z = xv.z * wv.z; ov.w = xv.w * wv.w;
            o[k] = ov;
            s += ov.x + ov.y + ov.z + ov.w;
            ss += ov.x * ov.x + ov.y * ov.y + ov.z * ov.z + ov.w * ov.w;
        }
        #pragma unroll
        for (int off = 32; off; off >>= 1) {
            s += __shfl_down(s, off, 64);
            ss += __shfl_down(ss, off, 64);
        }
        int wave = tid >> 6, lane = tid & 63;
        if (lane == 0) { ls[wave] = s; lss[wave] = ss; }
        __syncthreads();
        if (tid == 0) {
            float S = ls[0] + ls[1] + ls[2] + ls[3];
            float SS = lss[0] + lss[1] + lss[2] + lss[3];
            float mu = S * (1.f / HWP);
            float var = fmaxf(SS * (1.f / HWP) - mu * mu, 0.f);
            sstat[0] = mu;
            sstat[1] = rsqrtf(var + 1e-5f);
        }
        __syncthreads();
        float mu = sstat[0];
        float g5 = 5.f * sstat[1] * gamma[c];
        float b5 = 5.f * beta[c];
        float* op = out + (size_t)bc * HWP;
        #pragma unroll
        for (int k = 0; k < 16; k++) {
            int idx = tid + k * 256;
            float4 ov = o[k];
            f32x4_t r;
            r.x = fmaxf(fmaf(ov.x - mu, g5, b5), 0.f);
            r.y = fmaxf(fmaf(ov.y - mu, g5, b5), 0.f);
            r.z = fmaxf(fmaf(ov.z - mu, g5, b5), 0.f);
            r.w = fmaxf(fmaf(ov.w - mu, g5, b5), 0.f);
            __builtin_nontemporal_store(r, ((f32x4_t*)op) + idx);
        }
    }
}

// ---------------------------------------------------------------------------
// Fallback path: original 3-kernel pipeline (used only if cooperative launch
// is rejected by the runtime).
// ---------------------------------------------------------------------------
__global__ __launch_bounds__(256) void k1(const float* __restrict__ masks,
                                          const float* __restrict__ x,
                                          float* __restrict__ m_out,
                                          float* __restrict__ cs,
                                          float* __restrict__ cm) {
    int bid = blockIdx.x, tid = threadIdx.x;
    if ((bid & 1) == 0) {
        int t = (bid >> 1) * 256 + tid;
        int j = t & 127, i = (t >> 7) & 127, b = t >> 14;
        const float Wt[8] = {1.f, 3.f, 5.f, 7.f, 7.f, 5.f, 3.f, 1.f};
        const float* mb = masks + (size_t)b * (MH * MW);
        int r0 = 4 * i - 2, c0 = 4 * j - 2;
        float cwgt[8];
        int ccl[8];
        float sh = 0.f;
        #pragma unroll
        for (int q = 0; q < 8; q++) {
            int c = c0 + q;
            bool v = (unsigned)c < (unsigned)MW;
            cwgt[q] = v ? Wt[q] : 0.f;
            sh += cwgt[q];
            ccl[q] = min(max(c, 0), MW - 1);
        }
        float acc = 0.f, sv = 0.f;
        #pragma unroll
        for (int p = 0; p < 8; p++) {
            int r = r0 + p;
            bool v = (unsigned)r < (unsigned)MH;
            float wp = v ? Wt[p] : 0.f;
            sv += wp;
            const float* row = mb + (size_t)min(max(r, 0), MH - 1) * MW;
            float ra = 0.f;
            #pragma unroll
            for (int q = 0; q < 8; q++) ra += cwgt[q] * row[ccl[q]];
            acc += wp * ra;
        }
        m_out[t] = acc / (sv * sh);
    } else {
        int id = bid >> 1;
        int chunk = id & 15;
        int g = (id >> 4) & 3;
        int b = id >> 6;
        int qi = chunk * 256 + tid;
        const float4* xb = (const float4*)x + ((size_t)(b * CC + g * 64)) * IQ + qi;
        float4 s = {0.f, 0.f, 0.f, 0.f};
        float4 mx = {-INFINITY, -INFINITY, -INFINITY, -INFINITY};
        #pragma unroll 8
        for (int c = 0; c < 64; c++) {
            float4 v = xb[(size_t)c * IQ];
            s.x += v.x; s.y += v.y; s.z += v.z; s.w += v.w;
            mx.x = fmaxf(mx.x, v.x); mx.y = fmaxf(mx.y, v.y);
            mx.z = fmaxf(mx.z, v.z); mx.w = fmaxf(mx.w, v.w);
        }
        size_t o = (size_t)g * (NPIX / 4) + (size_t)b * IQ + qi;
        ((float4*)cs)[o] = s;
        ((float4*)cm)[o] = mx;
    }
}

__global__ __launch_bounds__(256) void k2(const float* __restrict__ m,
                                          const float* __restrict__ cs,
                                          const float* __restrict__ cm,
                                          const float* __restrict__ cw,
                                          float* __restrict__ wprod) {
    __shared__ float w[147];
    __shared__ float pa[IH * PITCH], px[IH * PITCH], pm[IH * PITCH];
    int tid = threadIdx.x, bid = blockIdx.x;
    int bx = bid & 1, by = (bid >> 1) & 31, b = bid >> 6;
    if (tid < 147) w[tid] = cw[tid];
    int ox = bx * TW - 3, oy = by * TH - 3;
    for (int idx = tid; idx < IW * IH; idx += 256) {
        int r = idx / IW, c = idx - r * IW;
        int gi = oy + r, gj = ox + c;
        float av = 0.f, mxv = 0.f, mv = 0.f;
        if ((unsigned)gi < (unsigned)HH && (unsigned)gj < (unsigned)WW) {
            int p = b * HWP + gi * WW + gj;
            mv = m[p];
            float s = cs[p] + cs[p + NPIX] + cs[p + 2 * NPIX] + cs[p + 3 * NPIX];
            float mmx = fmaxf(fmaxf(cm[p], cm[p + NPIX]),
                              fmaxf(cm[p + 2 * NPIX], cm[p + 3 * NPIX]));
            av = mv * s * (1.f / 256.f);
            mxv = mv * mmx;
        }
        pa[r * PITCH + c] = av;
        px[r * PITCH + c] = mxv;
        pm[r * PITCH + c] = mv;
    }
    __syncthreads();
    int col = tid & 63, r = tid >> 6;
    float acc = 0.f;
    #pragma unroll
    for (int di = 0; di < 7; di++) {
        #pragma unroll
        for (int dj = 0; dj < 7; dj++) {
            int li = (r + di) * PITCH + col + dj;
            acc += w[di * 7 + dj] * pa[li];
            acc += w[49 + di * 7 + dj] * px[li];
            acc += w[98 + di * 7 + dj] * pm[li];
        }
    }
    float at = 1.f / (1.f + expf(-acc));
    float res = pm[(r + 3) * PITCH + col + 3] * at;
    wprod[b * HWP + (by * TH + r) * WW + bx * TW + col] = res;
}

__global__ __launch_bounds__(256) void k3(const float* __restrict__ x,
                                          const float* __restrict__ wprod,
                                          const float* __restrict__ gamma,
                                          const float* __restrict__ beta,
                                          float* __restrict__ out) {
    int bc = blockIdx.x;
    int b = bc >> 8, c = bc & 255;
    const float4* xp = (const float4*)(x + (size_t)bc * HWP);
    const float4* wp = (const float4*)(wprod + (size_t)b * HWP);
    float4 o[16];
    float s = 0.f, ss = 0.f;
    #pragma unroll
    for (int k = 0; k < 16; k++) {
        int idx = threadIdx.x + k * 256;
        float4 xv = xp[idx];
        float4 wv = wp[idx];
        float4 ov;
        ov.x = xv.x * wv.x; ov.y = xv.y * wv.y;
        ov.z = xv.z * wv.z; ov.w = xv.w * wv.w;
        o[k] = ov;
        s += ov.x + ov.y + ov.z + ov.w;
        ss += ov.x * ov.x + ov.y * ov.y + ov.z * ov.z + ov.w * ov.w;
    }
    #pragma unroll
    for (int off = 32; off; off >>= 1) {
        s += __shfl_down(s, off, 64);
        ss += __shfl_down(ss, off, 64);
    }
    __shared__ float ls[4], lss[4];
    __shared__ float smu, srs;
    int wave = threadIdx.x >> 6, lane = threadIdx.x & 63;
    if (lane == 0) { ls[wave] = s; lss[wave] = ss; }
    __syncthreads();
    if (threadIdx.x == 0) {
        float S = ls[0] + ls[1] + ls[2] + ls[3];
        float SS = lss[0] + lss[1] + lss[2] + lss[3];
        float mu = S * (1.f / HWP);
        float var = fmaxf(SS * (1.f / HWP) - mu * mu, 0.f);
        smu = mu;
        srs = rsqrtf(var + 1e-5f);
    }
    __syncthreads();
    float mu = smu;
    float g5 = 5.f * srs * gamma[c];
    float b5 = 5.f * beta[c];
    float4* op = (float4*)(out + (size_t)bc * HWP);
    #pragma unroll
    for (int k = 0; k < 16; k++) {
        int idx = threadIdx.x + k * 256;
        float4 ov = o[k], r;
        r.x = fmaxf(fmaf(ov.x - mu, g5, b5), 0.f);
        r.y = fmaxf(fmaf(ov.y - mu, g5, b5), 0.f);
        r.z = fmaxf(fmaf(ov.z - mu, g5, b5), 0.f);
        r.w = fmaxf(fmaf(ov.w - mu, g5, b5), 0.f);
        op[idx] = r;
    }
}

extern "C" void kernel_launch(void* const* d_in, const int* in_sizes, int n_in,
                              void* d_out, int out_size, void* d_ws, size_t ws_size,
                              hipStream_t stream) {
    const float* x      = (const float*)d_in[0];
    const float* masks  = (const float*)d_in[1];
    const float* conv_w = (const float*)d_in[2];
    const float* gamma  = (const float*)d_in[3];
    const float* beta   = (const float*)d_in[4];
    float* outp = (float*)d_out;

    float* ws = (float*)d_ws;
    float* m_arr = ws;                       // [NPIX]
    float* cs    = ws + (size_t)NPIX;        // [4*NPIX]
    float* cm    = ws + (size_t)5 * NPIX;    // [4*NPIX]
    float* wprod = ws + (size_t)9 * NPIX;    // [NPIX]

    void* args[] = {(void*)&masks, (void*)&x, (void*)&conv_w, (void*)&gamma,
                    (void*)&beta, (void*)&outp, (void*)&m_arr, (void*)&cs,
                    (void*)&cm, (void*)&wprod};
    hipError_t err = hipLaunchCooperativeKernel((const void*)fused, dim3(1024),
                                                dim3(256), args, 0, stream);
    if (err != hipSuccess) {
        // Fallback: original verified 3-kernel pipeline.
        k1<<<1024, 256, 0, stream>>>(masks, x, m_arr, cs, cm);
        k2<<<512, 256, 0, stream>>>(m_arr, cs, cm, conv_w, wprod);
        k3<<<BB * CC, 256, 0, stream>>>(x, wprod, gamma, beta, outp);
    }
}

// Round 2
// 274.534 us; speedup vs baseline: 2.6117x; 2.6117x over previous
//
#include <hip/hip_runtime.h>
#include <math.h>

#define BB 8
#define CC 256
#define HH 128
#define WW 128
#define HWP 16384          // 128*128
#define MH 512
#define MW 512
#define NPIX (BB*HWP)      // 131072
#define IQ 4096            // HWP/4 quads per image

typedef float f32x4_t __attribute__((ext_vector_type(4)));

// ---------------------------------------------------------------------------
// K1: 1536 blocks.
//   blocks 0..1023   : x channel partial sum/max, 32 channels each ->
//                      cs/cm [8][NPIX] partials. Dispatched FIRST so the
//                      HBM-bound long pole owns the machine from t=0.
//   blocks 1024..1535: antialias 512->128 mask resize, branchless.
// ---------------------------------------------------------------------------
__global__ __launch_bounds__(256) void k1(const float* __restrict__ masks,
                                          const float* __restrict__ x,
                                          float* __restrict__ m_out,
                                          float* __restrict__ cs,
                                          float* __restrict__ cm) {
    int bid = blockIdx.x, tid = threadIdx.x;
    if (bid < 1024) {
        // ---- channel partial-reduce path: id = b(3) | g8(3) | chunk(4) ----
        int id = bid;
        int chunk = id & 15;
        int g8 = (id >> 4) & 7;
        int b = id >> 7;
        int qi = chunk * 256 + tid;      // quad index within image, 0..4095
        const float4* xb = (const float4*)x + ((size_t)(b * CC + g8 * 32)) * IQ + qi;
        float4 s = {0.f, 0.f, 0.f, 0.f};
        float4 mx = {-INFINITY, -INFINITY, -INFINITY, -INFINITY};
        #pragma unroll 8
        for (int c = 0; c < 32; c++) {
            float4 v = xb[(size_t)c * IQ];
            s.x += v.x; s.y += v.y; s.z += v.z; s.w += v.w;
            mx.x = fmaxf(mx.x, v.x); mx.y = fmaxf(mx.y, v.y);
            mx.z = fmaxf(mx.z, v.z); mx.w = fmaxf(mx.w, v.w);
        }
        size_t o = (size_t)g8 * (NPIX / 4) + (size_t)b * IQ + qi;
        ((float4*)cs)[o] = s;
        ((float4*)cm)[o] = mx;
    } else {
        // ---- mask resize path ----
        int t = (bid - 1024) * 256 + tid;          // 0..NPIX-1
        int j = t & 127, i = (t >> 7) & 127, b = t >> 14;
        const float Wt[8] = {1.f, 3.f, 5.f, 7.f, 7.f, 5.f, 3.f, 1.f};
        const float* mb = masks + (size_t)b * (MH * MW);
        int r0 = 4 * i - 2, c0 = 4 * j - 2;
        float cwgt[8];
        int ccl[8];
        float sh = 0.f;
        #pragma unroll
        for (int q = 0; q < 8; q++) {
            int c = c0 + q;
            bool v = (unsigned)c < (unsigned)MW;
            cwgt[q] = v ? Wt[q] : 0.f;
            sh += cwgt[q];
            ccl[q] = min(max(c, 0), MW - 1);
        }
        float acc = 0.f, sv = 0.f;
        #pragma unroll
        for (int p = 0; p < 8; p++) {
            int r = r0 + p;
            bool v = (unsigned)r < (unsigned)MH;
            float wp = v ? Wt[p] : 0.f;
            sv += wp;
            const float* row = mb + (size_t)min(max(r, 0), MH - 1) * MW;
            float ra = 0.f;
            #pragma unroll
            for (int q = 0; q < 8; q++) ra += cwgt[q] * row[ccl[q]];
            acc += wp * ra;
        }
        m_out[t] = acc / (sv * sh);
    }
}

// ---------------------------------------------------------------------------
// K2: fused combine(8 partials) + 7x7 conv + sigmoid -> wprod = m*sigmoid(conv)
// Block = 64x4 output tile, LDS halo 70x10 per plane (avg*m, max*m, m).
// ---------------------------------------------------------------------------
#define TW 64
#define TH 4
#define IW 70
#define IH 10
#define PITCH 72
__global__ __launch_bounds__(256) void k2(const float* __restrict__ m,
                                          const float* __restrict__ cs,
                                          const float* __restrict__ cm,
                                          const float* __restrict__ cw,
                                          float* __restrict__ wprod) {
    __shared__ float w[147];
    __shared__ float pa[IH * PITCH], px[IH * PITCH], pm[IH * PITCH];
    int tid = threadIdx.x, bid = blockIdx.x;
    int bx = bid & 1, by = (bid >> 1) & 31, b = bid >> 6;
    if (tid < 147) w[tid] = cw[tid];
    int ox = bx * TW - 3, oy = by * TH - 3;
    for (int idx = tid; idx < IW * IH; idx += 256) {
        int r = idx / IW, c = idx - r * IW;
        int gi = oy + r, gj = ox + c;
        float av = 0.f, mxv = 0.f, mv = 0.f;
        if ((unsigned)gi < (unsigned)HH && (unsigned)gj < (unsigned)WW) {
            int p = b * HWP + gi * WW + gj;
            mv = m[p];
            float s = 0.f, mmx = -INFINITY;
            #pragma unroll
            for (int g = 0; g < 8; g++) {
                s += cs[p + g * NPIX];
                mmx = fmaxf(mmx, cm[p + g * NPIX]);
            }
            av = mv * s * (1.f / 256.f);
            mxv = mv * mmx;
        }
        pa[r * PITCH + c] = av;
        px[r * PITCH + c] = mxv;
        pm[r * PITCH + c] = mv;
    }
    __syncthreads();
    int col = tid & 63, r = tid >> 6;
    float acc = 0.f;
    #pragma unroll
    for (int di = 0; di < 7; di++) {
        #pragma unroll
        for (int dj = 0; dj < 7; dj++) {
            int li = (r + di) * PITCH + col + dj;
            acc += w[di * 7 + dj] * pa[li];
            acc += w[49 + di * 7 + dj] * px[li];
            acc += w[98 + di * 7 + dj] * pm[li];
        }
    }
    float at = 1.f / (1.f + expf(-acc));
    float res = pm[(r + 3) * PITCH + col + 3] * at;
    wprod[b * HWP + (by * TH + r) * WW + bx * TW + col] = res;
}

// ---------------------------------------------------------------------------
// K3: final. One block per (b,c) plane. o = x*wprod cached in registers,
// block-reduce mean/var, instance-norm + relu(5*).
// out written with NONTEMPORAL stores: round-1 counters proved this keeps x
// L3-resident (single HBM fetch of x across the whole pipeline).
// ---------------------------------------------------------------------------
__global__ __launch_bounds__(256) void k3(const float* __restrict__ x,
                                          const float* __restrict__ wprod,
                                          const float* __restrict__ gamma,
                                          const float* __restrict__ beta,
                                          float* __restrict__ out) {
    int bc = blockIdx.x;          // b*256 + c
    int b = bc >> 8, c = bc & 255;
    const float4* xp = (const float4*)(x + (size_t)bc * HWP);
    const float4* wp = (const float4*)(wprod + (size_t)b * HWP);
    float4 o[16];
    float s = 0.f, ss = 0.f;
    #pragma unroll
    for (int k = 0; k < 16; k++) {
        int idx = threadIdx.x + k * 256;
        float4 xv = xp[idx];
        float4 wv = wp[idx];
        float4 ov;
        ov.x = xv.x * wv.x; ov.y = xv.y * wv.y;
        ov.z = xv.z * wv.z; ov.w = xv.w * wv.w;
        o[k] = ov;
        s += ov.x + ov.y + ov.z + ov.w;
        ss += ov.x * ov.x + ov.y * ov.y + ov.z * ov.z + ov.w * ov.w;
    }
    #pragma unroll
    for (int off = 32; off; off >>= 1) {
        s += __shfl_down(s, off, 64);
        ss += __shfl_down(ss, off, 64);
    }
    __shared__ float ls[4], lss[4];
    __shared__ float smu, srs;
    int wave = threadIdx.x >> 6, lane = threadIdx.x & 63;
    if (lane == 0) { ls[wave] = s; lss[wave] = ss; }
    __syncthreads();
    if (threadIdx.x == 0) {
        float S = ls[0] + ls[1] + ls[2] + ls[3];
        float SS = lss[0] + lss[1] + lss[2] + lss[3];
        float mu = S * (1.f / HWP);
        float var = fmaxf(SS * (1.f / HWP) - mu * mu, 0.f);
        smu = mu;
        srs = rsqrtf(var + 1e-5f);
    }
    __syncthreads();
    float mu = smu;
    float g5 = 5.f * srs * gamma[c];
    float b5 = 5.f * beta[c];
    f32x4_t* op = (f32x4_t*)(out + (size_t)bc * HWP);
    #pragma unroll
    for (int k = 0; k < 16; k++) {
        int idx = threadIdx.x + k * 256;
        float4 ov = o[k];
        f32x4_t r;
        r.x = fmaxf(fmaf(ov.x - mu, g5, b5), 0.f);
        r.y = fmaxf(fmaf(ov.y - mu, g5, b5), 0.f);
        r.z = fmaxf(fmaf(ov.z - mu, g5, b5), 0.f);
        r.w = fmaxf(fmaf(ov.w - mu, g5, b5), 0.f);
        __builtin_nontemporal_store(r, op + idx);
    }
}

extern "C" void kernel_launch(void* const* d_in, const int* in_sizes, int n_in,
                              void* d_out, int out_size, void* d_ws, size_t ws_size,
                              hipStream_t stream) {
    const float* x      = (const float*)d_in[0];
    const float* masks  = (const float*)d_in[1];
    const float* conv_w = (const float*)d_in[2];
    const float* gamma  = (const float*)d_in[3];
    const float* beta   = (const float*)d_in[4];
    float* out = (float*)d_out;

    float* ws = (float*)d_ws;
    float* m_arr = ws;                        // [NPIX]
    float* cs    = ws + (size_t)NPIX;         // [8*NPIX]
    float* cm    = ws + (size_t)9 * NPIX;     // [8*NPIX]
    float* wprod = ws + (size_t)17 * NPIX;    // [NPIX]

    k1<<<1536, 256, 0, stream>>>(masks, x, m_arr, cs, cm);
    k2<<<512, 256, 0, stream>>>(m_arr, cs, cm, conv_w, wprod);
    k3<<<BB * CC, 256, 0, stream>>>(x, wprod, gamma, beta, out);
}

// Round 3
// 264.397 us; speedup vs baseline: 2.7119x; 1.0383x over previous
//
#include <hip/hip_runtime.h>
#include <math.h>

#define BB 8
#define CC 256
#define HH 128
#define WW 128
#define HWP 16384          // 128*128
#define MH 512
#define MW 512
#define NPIX (BB*HWP)      // 131072
#define IQ 4096            // HWP/4 quads per image

typedef float f32x4_t __attribute__((ext_vector_type(4)));

// ---------------------------------------------------------------------------
// K1: heterogeneous grid, 1024 blocks interleaved (= exactly 4 blocks/CU, all
// co-resident so the VALU-heavy resize overlaps the HBM-heavy reduce).
//   even blocks: antialias 512->128 mask resize, branchless
//   odd  blocks: x channel partial sum/max, float4 loads, 4 groups of 64
//                channels -> cs/cm [4][NPIX]
// ---------------------------------------------------------------------------
__global__ __launch_bounds__(256) void k1(const float* __restrict__ masks,
                                          const float* __restrict__ x,
                                          float* __restrict__ m_out,
                                          float* __restrict__ cs,
                                          float* __restrict__ cm) {
    int bid = blockIdx.x, tid = threadIdx.x;
    if ((bid & 1) == 0) {
        // ---- mask resize path ----
        int t = (bid >> 1) * 256 + tid;            // 0..NPIX-1
        int j = t & 127, i = (t >> 7) & 127, b = t >> 14;
        const float Wt[8] = {1.f, 3.f, 5.f, 7.f, 7.f, 5.f, 3.f, 1.f};
        const float* mb = masks + (size_t)b * (MH * MW);
        int r0 = 4 * i - 2, c0 = 4 * j - 2;
        float cwgt[8];
        int ccl[8];
        float sh = 0.f;
        #pragma unroll
        for (int q = 0; q < 8; q++) {
            int c = c0 + q;
            bool v = (unsigned)c < (unsigned)MW;
            cwgt[q] = v ? Wt[q] : 0.f;
            sh += cwgt[q];
            ccl[q] = min(max(c, 0), MW - 1);
        }
        float acc = 0.f, sv = 0.f;
        #pragma unroll
        for (int p = 0; p < 8; p++) {
            int r = r0 + p;
            bool v = (unsigned)r < (unsigned)MH;
            float wp = v ? Wt[p] : 0.f;
            sv += wp;
            const float* row = mb + (size_t)min(max(r, 0), MH - 1) * MW;
            float ra = 0.f;
            #pragma unroll
            for (int q = 0; q < 8; q++) ra += cwgt[q] * row[ccl[q]];
            acc += wp * ra;
        }
        m_out[t] = acc / (sv * sh);
    } else {
        // ---- channel partial-reduce path ----
        int id = bid >> 1;               // 0..511 = b(3) | g(2) | chunk(4)
        int chunk = id & 15;
        int g = (id >> 4) & 3;
        int b = id >> 6;
        int qi = chunk * 256 + tid;      // quad index within image, 0..4095
        const float4* xb = (const float4*)x + ((size_t)(b * CC + g * 64)) * IQ + qi;
        float4 s = {0.f, 0.f, 0.f, 0.f};
        float4 mx = {-INFINITY, -INFINITY, -INFINITY, -INFINITY};
        #pragma unroll 8
        for (int c = 0; c < 64; c++) {
            float4 v = xb[(size_t)c * IQ];
            s.x += v.x; s.y += v.y; s.z += v.z; s.w += v.w;
            mx.x = fmaxf(mx.x, v.x); mx.y = fmaxf(mx.y, v.y);
            mx.z = fmaxf(mx.z, v.z); mx.w = fmaxf(mx.w, v.w);
        }
        size_t o = (size_t)g * (NPIX / 4) + (size_t)b * IQ + qi;
        ((float4*)cs)[o] = s;
        ((float4*)cm)[o] = mx;
    }
}

// ---------------------------------------------------------------------------
// K2: fused combine + 7x7 conv + sigmoid -> wprod = m * sigmoid(conv)
// Block = 64x4 output tile, LDS halo 70x10 per plane (avg*m, max*m, m).
// ---------------------------------------------------------------------------
#define TW 64
#define TH 4
#define IW 70
#define IH 10
#define PITCH 72
__global__ __launch_bounds__(256) void k2(const float* __restrict__ m,
                                          const float* __restrict__ cs,
                                          const float* __restrict__ cm,
                                          const float* __restrict__ cw,
                                          float* __restrict__ wprod) {
    __shared__ float w[147];
    __shared__ float pa[IH * PITCH], px[IH * PITCH], pm[IH * PITCH];
    int tid = threadIdx.x, bid = blockIdx.x;
    int bx = bid & 1, by = (bid >> 1) & 31, b = bid >> 6;
    if (tid < 147) w[tid] = cw[tid];
    int ox = bx * TW - 3, oy = by * TH - 3;
    for (int idx = tid; idx < IW * IH; idx += 256) {
        int r = idx / IW, c = idx - r * IW;
        int gi = oy + r, gj = ox + c;
        float av = 0.f, mxv = 0.f, mv = 0.f;
        if ((unsigned)gi < (unsigned)HH && (unsigned)gj < (unsigned)WW) {
            int p = b * HWP + gi * WW + gj;
            mv = m[p];
            float s = cs[p] + cs[p + NPIX] + cs[p + 2 * NPIX] + cs[p + 3 * NPIX];
            float mmx = fmaxf(fmaxf(cm[p], cm[p + NPIX]),
                              fmaxf(cm[p + 2 * NPIX], cm[p + 3 * NPIX]));
            av = mv * s * (1.f / 256.f);
            mxv = mv * mmx;
        }
        pa[r * PITCH + c] = av;
        px[r * PITCH + c] = mxv;
        pm[r * PITCH + c] = mv;
    }
    __syncthreads();
    int col = tid & 63, r = tid >> 6;
    float acc = 0.f;
    #pragma unroll
    for (int di = 0; di < 7; di++) {
        #pragma unroll
        for (int dj = 0; dj < 7; dj++) {
            int li = (r + di) * PITCH + col + dj;
            acc += w[di * 7 + dj] * pa[li];
            acc += w[49 + di * 7 + dj] * px[li];
            acc += w[98 + di * 7 + dj] * pm[li];
        }
    }
    float at = 1.f / (1.f + expf(-acc));
    float res = pm[(r + 3) * PITCH + col + 3] * at;
    wprod[b * HWP + (by * TH + r) * WW + bx * TW + col] = res;
}

// ---------------------------------------------------------------------------
// K3: final. One block per (b,c) plane. o = x*wprod cached in registers,
// block-reduce mean/var, instance-norm + relu(5*).
// x read with NT loads (last use), out written with NT stores so the 134 MB
// of output writes never evict x from L3 mid-kernel (round-1 counters: total
// pipeline FETCH was 156 MB with NT => x fetched from HBM exactly once).
// ---------------------------------------------------------------------------
__global__ __launch_bounds__(256) void k3(const float* __restrict__ x,
                                          const float* __restrict__ wprod,
                                          const float* __restrict__ gamma,
                                          const float* __restrict__ beta,
                                          float* __restrict__ out) {
    int bc = blockIdx.x;          // b*256 + c
    int b = bc >> 8, c = bc & 255;
    const f32x4_t* xp = (const f32x4_t*)(x + (size_t)bc * HWP);
    const float4* wp = (const float4*)(wprod + (size_t)b * HWP);
    f32x4_t o[16];
    float s = 0.f, ss = 0.f;
    #pragma unroll
    for (int k = 0; k < 16; k++) {
        int idx = threadIdx.x + k * 256;
        f32x4_t xv = __builtin_nontemporal_load(xp + idx);
        float4 wv = wp[idx];
        f32x4_t ov;
        ov.x = xv.x * wv.x; ov.y = xv.y * wv.y;
        ov.z = xv.z * wv.z; ov.w = xv.w * wv.w;
        o[k] = ov;
        s += ov.x + ov.y + ov.z + ov.w;
        ss += ov.x * ov.x + ov.y * ov.y + ov.z * ov.z + ov.w * ov.w;
    }
    #pragma unroll
    for (int off = 32; off; off >>= 1) {
        s += __shfl_down(s, off, 64);
        ss += __shfl_down(ss, off, 64);
    }
    __shared__ float ls[4], lss[4];
    __shared__ float smu, srs;
    int wave = threadIdx.x >> 6, lane = threadIdx.x & 63;
    if (lane == 0) { ls[wave] = s; lss[wave] = ss; }
    __syncthreads();
    if (threadIdx.x == 0) {
        float S = ls[0] + ls[1] + ls[2] + ls[3];
        float SS = lss[0] + lss[1] + lss[2] + lss[3];
        float mu = S * (1.f / HWP);
        float var = fmaxf(SS * (1.f / HWP) - mu * mu, 0.f);
        smu = mu;
        srs = rsqrtf(var + 1e-5f);
    }
    __syncthreads();
    float mu = smu;
    float g5 = 5.f * srs * gamma[c];
    float b5 = 5.f * beta[c];
    f32x4_t* op = (f32x4_t*)(out + (size_t)bc * HWP);
    #pragma unroll
    for (int k = 0; k < 16; k++) {
        int idx = threadIdx.x + k * 256;
        f32x4_t ov = o[k];
        f32x4_t r;
        r.x = fmaxf(fmaf(ov.x - mu, g5, b5), 0.f);
        r.y = fmaxf(fmaf(ov.y - mu, g5, b5), 0.f);
        r.z = fmaxf(fmaf(ov.z - mu, g5, b5), 0.f);
        r.w = fmaxf(fmaf(ov.w - mu, g5, b5), 0.f);
        __builtin_nontemporal_store(r, op + idx);
    }
}

extern "C" void kernel_launch(void* const* d_in, const int* in_sizes, int n_in,
                              void* d_out, int out_size, void* d_ws, size_t ws_size,
                              hipStream_t stream) {
    const float* x      = (const float*)d_in[0];
    const float* masks  = (const float*)d_in[1];
    const float* conv_w = (const float*)d_in[2];
    const float* gamma  = (const float*)d_in[3];
    const float* beta   = (const float*)d_in[4];
    float* out = (float*)d_out;

    float* ws = (float*)d_ws;
    float* m_arr = ws;                       // [NPIX]
    float* cs    = ws + (size_t)NPIX;        // [4*NPIX]
    float* cm    = ws + (size_t)5 * NPIX;    // [4*NPIX]
    float* wprod = ws + (size_t)9 * NPIX;    // [NPIX]

    k1<<<1024, 256, 0, stream>>>(masks, x, m_arr, cs, cm);
    k2<<<512, 256, 0, stream>>>(m_arr, cs, cm, conv_w, wprod);
    k3<<<BB * CC, 256, 0, stream>>>(x, wprod, gamma, beta, out);
}